// Round 7
// baseline (110.158 us; speedup 1.0000x reference)
//
#include <hip/hip_runtime.h>

// PointNet++ set abstraction: ball query (first-16-by-index within r=0.5) +
// gather + rel-coords/feat concat + 2-layer MLP (leaky 0.1) + max-pool.
// B=4, N=16384, M=4096, K=16.
//
// Round 7: offload the MLP's weight reads from the per-CU LDS pipe (was
// ~35us/CU of ds_read issue: 64 b128 W2 reads PER QUERY) to the idle VMEM
// pipe (W1/W2/b1/b2 read directly from global, L1-hot, broadcast addrs).
// LDS keeps only sNbr (256B) -> no __syncthreads, no LDS occupancy limit.
// Plus: 8-bucket descending scan-length order (bucket = floor(|q|^2)) so
// blocks are homogeneous (kills E[max4] ~2x residency inflation).
// Scan loop identical to round-6 (proven 65us). d2 math bit-identical to
// all passing rounds.

constexpr int N_PTS = 16384;
constexpr int M_Q   = 4096;
constexpr int KNN   = 16;
constexpr int TOTAL_Q = 4 * M_Q;     // 16384
constexpr int TOTAL_P = 4 * N_PTS;   // 65536
constexpr int NBKT   = 8;

// ---- ws layout ----
constexpr size_t WS_PKX   = 0;                                 // float4[65536] = 1MB
constexpr size_t WS_LISTS = WS_PKX + (size_t)TOTAL_P * 16;     // 8 x int[16384] = 512KB
constexpr size_t WS_CNTS  = WS_LISTS + (size_t)NBKT * TOTAL_Q * 4;  // int[8]
constexpr size_t WS_NEED  = WS_CNTS + 64;

// ------- pre-pass: pack points + build 8 descending-length buckets -------
__global__ __launch_bounds__(256) void prep_kernel(
    const float* __restrict__ xyz, const int* __restrict__ fps,
    float4* __restrict__ pkX, int* __restrict__ lists, int* __restrict__ cnts)
{
    const int i = blockIdx.x * 256 + threadIdx.x;
    const int lane = threadIdx.x & 63;
    const unsigned long long lt_mask = (1ull << lane) - 1ull;

    // pack points: {x,y,z,|p|^2} with the reference-exact sq expression
    if (i < TOTAL_P) {
        const float x = xyz[i * 3 + 0], y = xyz[i * 3 + 1], z = xyz[i * 3 + 2];
        const float sq = __fadd_rn(__fadd_rn(__fmul_rn(x, x), __fmul_rn(y, y)),
                                   __fmul_rn(z, z));
        pkX[i] = make_float4(x, y, z, sq);
    }

    // classify queries into 8 buckets by floor(|q|^2) (scan len ~ e^{s/2})
    if (i < TOTAL_Q) {
        const int b = i >> 12;
        const int pidx = fps[i];
        const size_t base3 = ((size_t)b * N_PTS + pidx) * 3;
        const float x = xyz[base3 + 0], y = xyz[base3 + 1], z = xyz[base3 + 2];
        const float s = __fadd_rn(__fadd_rn(__fmul_rn(x, x), __fmul_rn(y, y)),
                                  __fmul_rn(z, z));
        int key = (int)s;
        key = key < 0 ? 0 : (key > NBKT - 1 ? NBKT - 1 : key);

        #pragma unroll
        for (int bb = 0; bb < NBKT; ++bb) {
            const bool mine = (key == bb);
            const unsigned long long mk = __ballot(mine);
            if (mk) {                                  // wave-uniform
                int base = 0;
                if (lane == 0) base = atomicAdd(&cnts[bb], (int)__popcll(mk));
                base = __shfl(base, 0, 64);
                if (mine) lists[bb * TOTAL_Q + base + __popcll(mk & lt_mask)] = i;
            }
        }
    }
}

// ---------------- main fused kernel ----------------
#define LOAD8(R, P, P2)                                          \
    {                                                            \
        _Pragma("unroll")                                        \
        for (int j = 0; j < 4; ++j) R[j] = (P)[j * 64];          \
        _Pragma("unroll")                                        \
        for (int j = 0; j < 4; ++j) R[4 + j] = (P2)[j * 64];     \
    }

#define PROC8(R, CB)                                                          \
    {                                                                         \
        _Pragma("unroll")                                                     \
        for (int j = 0; j < 8; ++j) {                                         \
            float dot = __fmul_rn(qx, R[j].x);                                \
            dot = __builtin_fmaf(qy, R[j].y, dot);                            \
            dot = __builtin_fmaf(qz, R[j].z, dot);                            \
            const float d2 = __fsub_rn(__fadd_rn(sqq, R[j].w),                \
                                       __fmul_rn(2.0f, dot));                 \
            const bool hit = (d2 <= 0.25f);                                   \
            const unsigned long long mk = __ballot(hit);                      \
            if (hit) {                                                        \
                const int pos = count + __popcll(mk & lt_mask);               \
                if (pos < KNN) sNbr[wave][pos] = (CB) + j * 64 + lane;        \
            }                                                                 \
            count += (int)__popcll(mk);                                       \
        }                                                                     \
    }

__global__ __launch_bounds__(256) void pe_flow_main_kernel(
    const float4* __restrict__ pkX, const float* __restrict__ feat,
    const int*   __restrict__ fps,
    const int*   __restrict__ lists, const int* __restrict__ cnts,
    const float* __restrict__ W1, const float* __restrict__ b1,
    const float* __restrict__ W2, const float* __restrict__ b2,
    float* __restrict__ out)
{
    __shared__ int sNbr[4][KNN];

    const int tid  = threadIdx.x;
    const int wave = tid >> 6;
    const int lane = tid & 63;
    const unsigned long long lt_mask = (1ull << lane) - 1ull;

    // ---- select query: descending bucket order (longest scans first) ----
    const int w = blockIdx.x * 4 + wave;        // 0..16383
    int q = 0, off = 0;
    #pragma unroll
    for (int bb = NBKT - 1; bb >= 0; --bb) {
        const int c = cnts[bb];
        const int idx = w - off;
        if (idx >= 0 && idx < c) q = lists[bb * TOTAL_Q + idx];
        off += c;
    }
    const int b = q >> 12;

    const float4* pX = pkX + (size_t)b * N_PTS;

    const int pidx = fps[q];
    const float4 Q = pX[pidx];
    const float qx = Q.x, qy = Q.y, qz = Q.z, sqq = Q.w;

    // ---- ball query: first 16 in-radius indices, ascending ----
    // Two register banks of 8 float4 (512 pts each); prefetch across banks.
    int count = 0;
    {
        const float4* pA  = pX + lane;
        const float4* pA2 = pA + 256;
        const float4* pB  = pA + 512;
        const float4* pB2 = pA + 768;
        float4 ra[8], rb[8];

        LOAD8(ra, pA, pA2);
        __builtin_amdgcn_sched_barrier(0);

        for (int base = 0; base < N_PTS; base += 1024) {
            LOAD8(rb, pB, pB2);
            __builtin_amdgcn_sched_barrier(0);
            PROC8(ra, base);
            if (count >= KNN) break;            // wave-uniform

            pA += 1024; pA2 += 1024;
            if (base + 1024 < N_PTS) {
                LOAD8(ra, pA, pA2);
                __builtin_amdgcn_sched_barrier(0);
            }
            PROC8(rb, base + 512);
            if (count >= KNN) break;            // wave-uniform
            pB += 1024; pB2 += 1024;
        }
    }
    if (count < KNN) {
        const int first = sNbr[wave][0];   // count >= 1 (query point itself)
        if (lane >= count && lane < KNN) sNbr[wave][lane] = first;
    }

    // ---- fused MLP: 64 lanes = 16 neighbors x 4 channel-groups(8) ----
    // Weights read from GLOBAL (L1-hot broadcast) - not LDS (DS pipe was
    // the per-CU bottleneck at ~1.3K cyc/query of ds_read issue).
    const int k  = lane >> 2;
    const int co = (lane & 3) * 8;
    const int ni = sNbr[wave][k];

    const float4 gx = pX[ni];
    const size_t f3 = ((size_t)b * N_PTS + ni) * 3;
    const float in0 = gx.x - qx;
    const float in1 = gx.y - qy;
    const float in2 = gx.z - qz;
    const float in3 = feat[f3 + 0];
    const float in4 = feat[f3 + 1];
    const float in5 = feat[f3 + 2];
    const float in[6] = {in0, in1, in2, in3, in4, in5};

    float4 h1a = *(const float4*)(b1 + co);
    float4 h1b = *(const float4*)(b1 + co + 4);
    #pragma unroll
    for (int r = 0; r < 6; ++r) {
        const float4 wa = *(const float4*)(W1 + r * 32 + co);
        const float4 wb = *(const float4*)(W1 + r * 32 + co + 4);
        h1a.x += in[r] * wa.x; h1a.y += in[r] * wa.y;
        h1a.z += in[r] * wa.z; h1a.w += in[r] * wa.w;
        h1b.x += in[r] * wb.x; h1b.y += in[r] * wb.y;
        h1b.z += in[r] * wb.z; h1b.w += in[r] * wb.w;
    }
    float h1[8];
    h1[0] = h1a.x; h1[1] = h1a.y; h1[2] = h1a.z; h1[3] = h1a.w;
    h1[4] = h1b.x; h1[5] = h1b.y; h1[6] = h1b.z; h1[7] = h1b.w;
    #pragma unroll
    for (int i = 0; i < 8; ++i) h1[i] = (h1[i] >= 0.0f) ? h1[i] : 0.1f * h1[i];

    float4 h2a = *(const float4*)(b2 + co);
    float4 h2b = *(const float4*)(b2 + co + 4);
    const int baseLane = lane & ~3;
    #pragma unroll
    for (int jj = 0; jj < 8; ++jj) {
        #pragma unroll
        for (int g = 0; g < 4; ++g) {
            const float v = __shfl(h1[jj], baseLane + g, 64);
            const int row = g * 8 + jj;
            const float4 wa = *(const float4*)(W2 + row * 32 + co);
            const float4 wb = *(const float4*)(W2 + row * 32 + co + 4);
            h2a.x += v * wa.x; h2a.y += v * wa.y;
            h2a.z += v * wa.z; h2a.w += v * wa.w;
            h2b.x += v * wb.x; h2b.y += v * wb.y;
            h2b.z += v * wb.z; h2b.w += v * wb.w;
        }
    }

    float h2[8];
    h2[0] = h2a.x; h2[1] = h2a.y; h2[2] = h2a.z; h2[3] = h2a.w;
    h2[4] = h2b.x; h2[5] = h2b.y; h2[6] = h2b.z; h2[7] = h2b.w;
    #pragma unroll
    for (int i = 0; i < 8; ++i) {
        float v = h2[i];
        v = (v >= 0.0f) ? v : 0.1f * v;
        v = fmaxf(v, __shfl_xor(v, 4, 64));
        v = fmaxf(v, __shfl_xor(v, 8, 64));
        v = fmaxf(v, __shfl_xor(v, 16, 64));
        v = fmaxf(v, __shfl_xor(v, 32, 64));
        h2[i] = v;
    }

    if (k == 0) {
        float* op = out + (size_t)q * 32 + co;
        #pragma unroll
        for (int i = 0; i < 8; ++i) op[i] = h2[i];
    }
}

// ---------------- round-1 fallback (self-contained, proven PASS) ----------------
__global__ __launch_bounds__(256) void pe_flow_fused_kernel(
    const float* __restrict__ xyz, const float* __restrict__ feat,
    const int* __restrict__ fps,
    const float* __restrict__ W1, const float* __restrict__ b1,
    const float* __restrict__ W2, const float* __restrict__ b2,
    float* __restrict__ out)
{
    __shared__ float sW1[192];
    __shared__ float sW2[1024];
    __shared__ float sb1[32];
    __shared__ float sb2[32];
    __shared__ int   sNbr[4][KNN];

    const int tid = threadIdx.x;
    if (tid < 192) sW1[tid] = W1[tid];
    for (int i = tid; i < 1024; i += 256) sW2[i] = W2[i];
    if (tid < 32) { sb1[tid] = b1[tid]; sb2[tid] = b2[tid]; }
    __syncthreads();

    const int wave = tid >> 6;
    const int lane = tid & 63;
    const int q = blockIdx.x * 4 + wave;
    const int b = q >> 12;
    const int m = q & (M_Q - 1);

    const float* xb = xyz  + (size_t)b * N_PTS * 3;
    const float* fb = feat + (size_t)b * N_PTS * 3;

    const int pidx = fps[b * M_Q + m];
    const float qx = xb[pidx * 3 + 0];
    const float qy = xb[pidx * 3 + 1];
    const float qz = xb[pidx * 3 + 2];
    const float sq_q = __fadd_rn(__fadd_rn(__fmul_rn(qx, qx), __fmul_rn(qy, qy)),
                                 __fmul_rn(qz, qz));

    int count = 0;
    const unsigned long long lt_mask = (1ull << lane) - 1ull;
    for (int base = 0; base < N_PTS; base += 64) {
        const int i = base + lane;
        const float px = xb[i * 3 + 0];
        const float py = xb[i * 3 + 1];
        const float pz = xb[i * 3 + 2];
        const float sq_p = __fadd_rn(__fadd_rn(__fmul_rn(px, px), __fmul_rn(py, py)),
                                     __fmul_rn(pz, pz));
        float dot = __fmul_rn(qx, px);
        dot = __builtin_fmaf(qy, py, dot);
        dot = __builtin_fmaf(qz, pz, dot);
        const float d2 = __fsub_rn(__fadd_rn(sq_q, sq_p), __fmul_rn(2.0f, dot));
        const bool hit = (d2 <= 0.25f);
        const unsigned long long mk = __ballot(hit);
        if (hit) {
            const int pos = count + __popcll(mk & lt_mask);
            if (pos < KNN) sNbr[wave][pos] = i;
        }
        count += (int)__popcll(mk);
        if (count >= KNN) break;
    }
    if (count < KNN) {
        const int first = sNbr[wave][0];
        if (lane >= count && lane < KNN) sNbr[wave][lane] = first;
    }

    const int k = lane >> 2;
    const int co = (lane & 3) * 8;
    const int ni = sNbr[wave][k];

    const float in0 = xb[ni * 3 + 0] - qx;
    const float in1 = xb[ni * 3 + 1] - qy;
    const float in2 = xb[ni * 3 + 2] - qz;
    const float in3 = fb[ni * 3 + 0];
    const float in4 = fb[ni * 3 + 1];
    const float in5 = fb[ni * 3 + 2];

    float h1[8];
    #pragma unroll
    for (int i = 0; i < 8; ++i) {
        float a = sb1[co + i];
        a += in0 * sW1[0 * 32 + co + i];
        a += in1 * sW1[1 * 32 + co + i];
        a += in2 * sW1[2 * 32 + co + i];
        a += in3 * sW1[3 * 32 + co + i];
        a += in4 * sW1[4 * 32 + co + i];
        a += in5 * sW1[5 * 32 + co + i];
        h1[i] = (a >= 0.0f) ? a : 0.1f * a;
    }

    float h2[8];
    #pragma unroll
    for (int i = 0; i < 8; ++i) h2[i] = sb2[co + i];
    const int baseLane = lane & ~3;
    #pragma unroll
    for (int jj = 0; jj < 8; ++jj) {
        #pragma unroll
        for (int g = 0; g < 4; ++g) {
            const float v = __shfl(h1[jj], baseLane + g, 64);
            const int row = g * 8 + jj;
            #pragma unroll
            for (int i = 0; i < 8; ++i)
                h2[i] += v * sW2[row * 32 + co + i];
        }
    }

    #pragma unroll
    for (int i = 0; i < 8; ++i) {
        float v = h2[i];
        v = (v >= 0.0f) ? v : 0.1f * v;
        v = fmaxf(v, __shfl_xor(v, 4, 64));
        v = fmaxf(v, __shfl_xor(v, 8, 64));
        v = fmaxf(v, __shfl_xor(v, 16, 64));
        v = fmaxf(v, __shfl_xor(v, 32, 64));
        h2[i] = v;
    }

    if (k == 0) {
        float* op = out + (size_t)q * 32 + co;
        #pragma unroll
        for (int i = 0; i < 8; ++i) op[i] = h2[i];
    }
}

extern "C" void kernel_launch(void* const* d_in, const int* in_sizes, int n_in,
                              void* d_out, int out_size, void* d_ws, size_t ws_size,
                              hipStream_t stream) {
    const float* xyz  = (const float*)d_in[0];
    const float* feat = (const float*)d_in[1];
    const int*   fps  = (const int*)d_in[2];
    const float* W1   = (const float*)d_in[3];
    const float* b1   = (const float*)d_in[4];
    const float* W2   = (const float*)d_in[5];
    const float* b2   = (const float*)d_in[6];
    float* out = (float*)d_out;

    if (ws_size < WS_NEED) {
        // fallback: proven round-1 kernel, no workspace needed
        pe_flow_fused_kernel<<<TOTAL_Q / 4, 256, 0, stream>>>(
            xyz, feat, fps, W1, b1, W2, b2, out);
        return;
    }

    char* ws = (char*)d_ws;
    float4* pkX = (float4*)(ws + WS_PKX);
    int* lists  = (int*)(ws + WS_LISTS);
    int* cnts   = (int*)(ws + WS_CNTS);

    hipMemsetAsync(cnts, 0, NBKT * 4, stream);
    prep_kernel<<<TOTAL_P / 256, 256, 0, stream>>>(xyz, fps, pkX, lists, cnts);
    pe_flow_main_kernel<<<TOTAL_Q / 4, 256, 0, stream>>>(
        pkX, feat, fps, lists, cnts, W1, b1, W2, b2, out);
}